// Round 5
// baseline (451.160 us; speedup 1.0000x reference)
//
#include <hip/hip_runtime.h>

// Window attention, bf16-MFMA (R5): no x LDS staging, swizzled pow2 LDS tiles.
// 1 block = 1 window, 512 threads = 8 waves; waves (h,0),(h,1) share head h.
// LDS = 4 heads x 12KB (q[64][32] | k[64][32] | vT[32][64], XOR-swizzled) = 48KB
//   -> 3 blocks/CU (24 waves). ao[64][128] (16KB) overlays heads 0/1 after frag loads.
// Wave (h,half): QKV d-half=half (x frags straight from global, cvt in flight);
// QK^T+softmax (no max-subtract) for tj in {2half,2half+1}; PV own tj both d-halves
// (P in registers via 4-lane shfl exchange); out-proj co-block 16*(2h+half).

typedef __attribute__((ext_vector_type(8))) short bf16x8;
typedef __attribute__((ext_vector_type(4))) float f32x4;
typedef __attribute__((ext_vector_type(4))) __bf16 bf16x4;

#define MFMA16(a, b, c) __builtin_amdgcn_mfma_f32_16x16x32_bf16(a, b, c, 0, 0, 0)

__device__ __forceinline__ uint2 pack4bf(float a, float b, float c, float d) {
    bf16x4 v; v[0] = (__bf16)a; v[1] = (__bf16)b; v[2] = (__bf16)c; v[3] = (__bf16)d;
    union { bf16x4 v; uint2 u; } pun; pun.v = v; return pun.u;
}

__device__ __forceinline__ bf16x8 cvt8(float4 a, float4 b) {
    uint2 lo = pack4bf(a.x, a.y, a.z, a.w);
    uint2 hi = pack4bf(b.x, b.y, b.z, b.w);
    union { uint4 u; bf16x8 v; } p;
    p.u.x = lo.x; p.u.y = lo.y; p.u.z = hi.x; p.u.w = hi.y;
    return p.v;
}

__device__ __forceinline__ uint2 shfl_u2(uint2 v, int src) {
    uint2 r;
    r.x = (unsigned)__shfl((int)v.x, src, 64);
    r.y = (unsigned)__shfl((int)v.y, src, 64);
    return r;
}

// Swizzled offsets (ushort units). 16B slots XORed within a row -> conflict-free
// b128 reads at min cycles (verified by bank-group analysis for all uses below).
__device__ __forceinline__ int qk_off(int tok, int d) {          // [64][32] bf16
    return (tok << 5) + ((((d >> 3) ^ (tok & 3)) << 3)) + (d & 7);
}
__device__ __forceinline__ int vt_off(int d, int tok) {          // [32][64] bf16
    return (d << 6) + ((((tok >> 3) ^ (d & 7)) << 3)) + (tok & 7);
}
__device__ __forceinline__ int ao_off(int tok, int c) {          // [64][128] bf16
    int s = c >> 3;
    s = (s & 8) | ((s & 7) ^ (tok & 7));
    return (tok << 7) + (s << 3) + (c & 7);
}

// ---- prep: weights fp32->bf16; bias repacked bf16 [h][nq][g][ti*4+r] * log2(e) ----
__global__ void prep_kernel(const float* __restrict__ qkv_w,
                            const float* __restrict__ proj_w,
                            const float* __restrict__ bias_table,
                            ushort* __restrict__ wq_bf,
                            ushort* __restrict__ wp_bf,
                            ushort* __restrict__ biasb) {
    int i = blockIdx.x * 256 + threadIdx.x;
    if (i < 49152) {
        union { __bf16 b; ushort s; } u; u.b = (__bf16)qkv_w[i];
        wq_bf[i] = u.s;
    }
    if (i < 16384) {
        union { __bf16 b; ushort s; } u; u.b = (__bf16)proj_w[i];
        wp_bf[i] = u.s;
        // biasb layout: i = ((h*64+nq)*4+g)*16 + ti*4 + r ; nk = 16*ti+4*g+r
        int h = i >> 12, nq = (i >> 6) & 63, g = (i >> 4) & 3, ti = (i >> 2) & 3, r = i & 3;
        int nk = 16 * ti + 4 * g + r;
        int idx = ((nq >> 3) - (nk >> 3) + 7) * 15 + ((nq & 7) - (nk & 7) + 7);
        union { __bf16 b; ushort s; } ub;
        ub.b = (__bf16)(bias_table[idx * 4 + h] * 1.4426950408889634f);
        biasb[i] = ub.s;
    }
}

__global__ __launch_bounds__(512, 6)
void winattn_mfma(const float* __restrict__ x,
                  const float* __restrict__ qkv_b,
                  const float* __restrict__ proj_b,
                  const ushort* __restrict__ wq_bf,
                  const ushort* __restrict__ wp_bf,
                  const ushort* __restrict__ biasb,
                  float* __restrict__ out) {
    __shared__ ushort hb[4][6144];   // per head: q[2048] | k[2048] | vT[2048] (swizzled)

    const int tid = threadIdx.x;
    const size_t w = blockIdx.x;
    const int h    = __builtin_amdgcn_readfirstlane(tid >> 7);        // 0..3 head
    const int half = __builtin_amdgcn_readfirstlane((tid >> 6) & 1);  // 0..1 wave-in-pair
    const int l  = tid & 63;
    const int g  = (l >> 4) & 3;  // 0..3
    const int cn = l & 15;        // 0..15

    ushort* qL  = hb[h];
    ushort* kL  = hb[h] + 2048;
    ushort* vT  = hb[h] + 4096;
    ushort* aoL = hb[0];          // ao[64][128] overlays heads 0..1 after barrier (2)

    const float* xg = x + w * 8192;

    // ---- stage B: QKV projection, d-half = half; x frags direct from global ----
    {
        f32x4 aq[4], ak[4], av[4];
        #pragma unroll
        for (int tn = 0; tn < 4; ++tn) {
            aq[tn] = (f32x4){0.f, 0.f, 0.f, 0.f};
            ak[tn] = (f32x4){0.f, 0.f, 0.f, 0.f};
            av[tn] = (f32x4){0.f, 0.f, 0.f, 0.f};
        }
        const int wrow = 32 * h + 16 * half + cn;
        #pragma unroll 2
        for (int kc = 0; kc < 4; ++kc) {
            bf16x8 xf[4];
            #pragma unroll
            for (int tn = 0; tn < 4; ++tn) {
                const float* xp = xg + (16 * tn + cn) * 128 + 8 * g + 32 * kc;
                xf[tn] = cvt8(*(const float4*)xp, *(const float4*)(xp + 4));
            }
            const bf16x8 wq = *(const bf16x8*)&wq_bf[(size_t)(wrow      ) * 128 + 8 * g + 32 * kc];
            const bf16x8 wk = *(const bf16x8*)&wq_bf[(size_t)(wrow + 128) * 128 + 8 * g + 32 * kc];
            const bf16x8 wv = *(const bf16x8*)&wq_bf[(size_t)(wrow + 256) * 128 + 8 * g + 32 * kc];
            #pragma unroll
            for (int tn = 0; tn < 4; ++tn) {
                aq[tn] = MFMA16(wq, xf[tn], aq[tn]);   // D[d][tok]
                ak[tn] = MFMA16(wk, xf[tn], ak[tn]);   // D[d][tok]
                av[tn] = MFMA16(xf[tn], wv, av[tn]);   // D[tok][d]
            }
        }
        const float4 bq = *(const float4*)&qkv_b[      32 * h + 16 * half + 4 * g];
        const float4 bk = *(const float4*)&qkv_b[128 + 32 * h + 16 * half + 4 * g];
        const float  bv = qkv_b[256 + 32 * h + 16 * half + cn];
        #pragma unroll
        for (int tn = 0; tn < 4; ++tn) {
            f32x4 q4 = aq[tn], k4 = ak[tn], v4 = av[tn];
            // q/k: tok = 16tn+cn, d = 16half+4g+r
            *(uint2*)&qL[qk_off(16 * tn + cn, 16 * half + 4 * g)] =
                pack4bf(q4[0] + bq.x, q4[1] + bq.y, q4[2] + bq.z, q4[3] + bq.w);
            *(uint2*)&kL[qk_off(16 * tn + cn, 16 * half + 4 * g)] =
                pack4bf(k4[0] + bk.x, k4[1] + bk.y, k4[2] + bk.z, k4[3] + bk.w);
            // v: d = 16half+cn, tok = 16tn+4g+r
            *(uint2*)&vT[vt_off(16 * half + cn, 16 * tn + 4 * g)] =
                pack4bf(v4[0] + bv, v4[1] + bv, v4[2] + bv, v4[3] + bv);
        }
    }
    __syncthreads();                                   // (1) q/k/v ready

    // ---- frag loads (must finish before ao overlay) ----
    bf16x8 ka[4], qa[2], va[2][2];
    #pragma unroll
    for (int t = 0; t < 4; ++t)
        ka[t] = *(const bf16x8*)&kL[qk_off(16 * t + cn, 8 * g)];
    #pragma unroll
    for (int j2 = 0; j2 < 2; ++j2)
        qa[j2] = *(const bf16x8*)&qL[qk_off(16 * (2 * half + j2) + cn, 8 * g)];
    #pragma unroll
    for (int ta = 0; ta < 2; ++ta)
        #pragma unroll
        for (int kk = 0; kk < 2; ++kk)
            va[ta][kk] = *(const bf16x8*)&vT[vt_off(16 * ta + cn, 8 * g + 32 * kk)];
    __syncthreads();                                   // (2) frag reads drained -> ao may overlay

    // ---- QK^T (swapped, own tj pair) ----
    f32x4 s[4][2];
    #pragma unroll
    for (int ti = 0; ti < 4; ++ti)
        #pragma unroll
        for (int j2 = 0; j2 < 2; ++j2)
            s[ti][j2] = (f32x4){0.f, 0.f, 0.f, 0.f};
    #pragma unroll
    for (int ti = 0; ti < 4; ++ti)
        #pragma unroll
        for (int j2 = 0; j2 < 2; ++j2)
            s[ti][j2] = MFMA16(ka[ti], qa[j2], s[ti][j2]);   // D[nk][nq]

    // ---- bias load (after QK^T to bound live regs) ----
    uint4 bb[2][2];
    #pragma unroll
    for (int j2 = 0; j2 < 2; ++j2) {
        const int nq = 16 * (2 * half + j2) + cn;
        const ushort* bp = biasb + (((h * 64 + nq) * 4 + g) << 4);
        bb[j2][0] = *(const uint4*)bp;
        bb[j2][1] = *(const uint4*)(bp + 8);
    }

    // ---- softmax (no max-subtract) + in-register P exchange ----
    bf16x8 pbf[2][2];
    {
        const float SCALE2 = 0.17677669529663687f * 1.4426950408889634f;  // scale*log2(e)
        const int esrc = ((l & 16) << 1) + cn;   // lane 32*(g&1)+cn
        const int osrc = esrc + 16;
        const bool hi = (l & 32) != 0;           // g>=2
        #pragma unroll
        for (int j2 = 0; j2 < 2; ++j2) {
            float sum = 0.f;
            #pragma unroll
            for (int ti = 0; ti < 4; ++ti) {
                const uint4 q4 = bb[j2][ti >> 1];
                const unsigned w0 = (ti & 1) ? q4.z : q4.x;
                const unsigned w1 = (ti & 1) ? q4.w : q4.y;
                const float b0 = __uint_as_float(w0 << 16);
                const float b1 = __uint_as_float(w0 & 0xffff0000u);
                const float b2 = __uint_as_float(w1 << 16);
                const float b3 = __uint_as_float(w1 & 0xffff0000u);
                f32x4 sv = s[ti][j2];
                sv[0] = exp2f(fmaf(sv[0], SCALE2, b0));
                sv[1] = exp2f(fmaf(sv[1], SCALE2, b1));
                sv[2] = exp2f(fmaf(sv[2], SCALE2, b2));
                sv[3] = exp2f(fmaf(sv[3], SCALE2, b3));
                s[ti][j2] = sv;
                sum += (sv[0] + sv[1]) + (sv[2] + sv[3]);
            }
            sum += __shfl_xor(sum, 16, 64);
            sum += __shfl_xor(sum, 32, 64);
            const float rs = 1.0f / sum;
            uint2 pk[4];
            #pragma unroll
            for (int ti = 0; ti < 4; ++ti) {
                f32x4 sv = s[ti][j2];
                pk[ti] = pack4bf(sv[0] * rs, sv[1] * rs, sv[2] * rs, sv[3] * rs);
            }
            // exchange among 4 lanes {cn+16g}: lane g, slot kk gets
            //   A = pk[(g>>1)+2kk] from lane 32*(g&1)+cn, B = same ti from +16.
            #pragma unroll
            for (int kk = 0; kk < 2; ++kk) {
                uint2 a0 = shfl_u2(pk[2 * kk    ], esrc);
                uint2 a1 = shfl_u2(pk[2 * kk + 1], esrc);
                uint2 b0 = shfl_u2(pk[2 * kk    ], osrc);
                uint2 b1 = shfl_u2(pk[2 * kk + 1], osrc);
                uint2 A; A.x = hi ? a1.x : a0.x; A.y = hi ? a1.y : a0.y;
                uint2 B; B.x = hi ? b1.x : b0.x; B.y = hi ? b1.y : b0.y;
                union { uint4 u; bf16x8 v; } pun;
                pun.u.x = A.x; pun.u.y = A.y; pun.u.z = B.x; pun.u.w = B.y;
                pbf[j2][kk] = pun.v;   // P[nq=16tj+cn][nk = 8g+32kk .. +7], normalized
            }
        }
    }

    // ---- PV (swapped): D[d][nq], both d-halves, own tj pair ----
    {
        f32x4 o[2][2];
        #pragma unroll
        for (int ta = 0; ta < 2; ++ta)
            #pragma unroll
            for (int j2 = 0; j2 < 2; ++j2)
                o[ta][j2] = (f32x4){0.f, 0.f, 0.f, 0.f};
        #pragma unroll
        for (int kk = 0; kk < 2; ++kk)
            #pragma unroll
            for (int ta = 0; ta < 2; ++ta)
                #pragma unroll
                for (int j2 = 0; j2 < 2; ++j2)
                    o[ta][j2] = MFMA16(va[ta][kk], pbf[j2][kk], o[ta][j2]);
        // ao: tok = 16(2half+j2)+cn, c = 32h+16ta+4g+r
        #pragma unroll
        for (int ta = 0; ta < 2; ++ta)
            #pragma unroll
            for (int j2 = 0; j2 < 2; ++j2) {
                f32x4 ov = o[ta][j2];
                *(uint2*)&aoL[ao_off(16 * (2 * half + j2) + cn, 32 * h + 16 * ta + 4 * g)] =
                    pack4bf(ov[0], ov[1], ov[2], ov[3]);
            }
    }
    __syncthreads();                                   // (3) ao ready

    // ---- out projection (swapped), co-block 16*(2h+half) ----
    {
        f32x4 po[4];
        #pragma unroll
        for (int tj = 0; tj < 4; ++tj)
            po[tj] = (f32x4){0.f, 0.f, 0.f, 0.f};
        const int prow = 16 * (2 * h + half) + cn;
        #pragma unroll
        for (int kc = 0; kc < 4; ++kc) {
            bf16x8 aof[4];
            #pragma unroll
            for (int tj = 0; tj < 4; ++tj)
                aof[tj] = *(const bf16x8*)&aoL[ao_off(16 * tj + cn, 8 * g + 32 * kc)];
            const bf16x8 pf = *(const bf16x8*)&wp_bf[(size_t)prow * 128 + 8 * g + 32 * kc];
            #pragma unroll
            for (int tj = 0; tj < 4; ++tj)
                po[tj] = MFMA16(pf, aof[tj], po[tj]);
        }
        float* og = out + w * 8192;
        const int co0 = 16 * (2 * h + half) + 4 * g;
        const float4 pb4 = *(const float4*)&proj_b[co0];
        #pragma unroll
        for (int tj = 0; tj < 4; ++tj) {
            f32x4 pv = po[tj];
            float4 ov;
            ov.x = pv[0] + pb4.x; ov.y = pv[1] + pb4.y;
            ov.z = pv[2] + pb4.z; ov.w = pv[3] + pb4.w;
            *(float4*)&og[(16 * tj + cn) * 128 + co0] = ov;
        }
    }
}

extern "C" void kernel_launch(void* const* d_in, const int* in_sizes, int n_in,
                              void* d_out, int out_size, void* d_ws, size_t ws_size,
                              hipStream_t stream) {
    const float* x          = (const float*)d_in[0];
    const float* qkv_w      = (const float*)d_in[1];
    const float* qkv_b      = (const float*)d_in[2];
    const float* proj_w     = (const float*)d_in[3];
    const float* proj_b     = (const float*)d_in[4];
    const float* bias_table = (const float*)d_in[5];
    float* out = (float*)d_out;

    // ws layout: [0,98304) qkv_w bf16 | [98304,131072) proj_w bf16 | [131072,163840) biasb bf16
    ushort* wq_bf = (ushort*)d_ws;
    ushort* wp_bf = (ushort*)((char*)d_ws + 98304);
    ushort* biasb = (ushort*)((char*)d_ws + 131072);

    prep_kernel<<<dim3(192), dim3(256), 0, stream>>>(qkv_w, proj_w, bias_table, wq_bf, wp_bf, biasb);
    winattn_mfma<<<dim3(4096), dim3(512), 0, stream>>>(x, qkv_b, proj_b, wq_bf, wp_bf, biasb, out);
}

// Round 6
// 117.591 us; speedup vs baseline: 3.8367x; 3.8367x over previous
//
#include <hip/hip_runtime.h>

// Window attention, bf16-MFMA (R6): single 48KB LDS arena, time-multiplexed.
//   phase 1: xs[64][128]bf16 (16KB, in q-region) - x staging for QKV
//   phase 2: q[4][64][32] | k[4][64][32] | vT[4][32][64] (48KB, swizzled)
//   phase 3: ao[64][128] (16KB, overlays vT region)
// 48KB -> 3 blocks/CU (24 waves). launch_bounds(512,3): 2nd arg = min BLOCKS/CU
// (CUDA semantics per R5 evidence: (512,6) gave VGPR cap 40 = 12 waves/SIMD).
// 1 block = 1 window, 8 waves; waves (h,0),(h,1) share head h. P unnormalized in
// bf16; 1/sum folded into lane-local PV epilogue. 5 barriers.

typedef __attribute__((ext_vector_type(8))) short bf16x8;
typedef __attribute__((ext_vector_type(4))) float f32x4;
typedef __attribute__((ext_vector_type(4))) __bf16 bf16x4;

#define MFMA16(a, b, c) __builtin_amdgcn_mfma_f32_16x16x32_bf16(a, b, c, 0, 0, 0)

__device__ __forceinline__ uint2 pack4bf(float a, float b, float c, float d) {
    bf16x4 v; v[0] = (__bf16)a; v[1] = (__bf16)b; v[2] = (__bf16)c; v[3] = (__bf16)d;
    union { bf16x4 v; uint2 u; } pun; pun.v = v; return pun.u;
}

__device__ __forceinline__ uint2 shfl_u2(uint2 v, int src) {
    uint2 r;
    r.x = (unsigned)__shfl((int)v.x, src, 64);
    r.y = (unsigned)__shfl((int)v.y, src, 64);
    return r;
}

// Bijective in-row XOR swizzles (ushort units), 16B-slot granularity.
__device__ __forceinline__ int qk_off(int tok, int d) {   // [64][32] bf16, row 64B
    return (tok << 5) + (((((d >> 3) & 3) ^ ((tok >> 1) & 3)) << 3)) + (d & 7);
}
__device__ __forceinline__ int vt_off(int d, int tok) {   // [32][64] bf16, row 128B
    return (d << 6) + (((((tok >> 3) & 7) ^ (d & 7)) << 3)) + (tok & 7);
}
__device__ __forceinline__ int ao_off(int tok, int c) {   // [64][128] bf16, row 256B
    return (tok << 7) + (((((c >> 3) & 15) ^ (tok & 7)) << 3)) + (c & 7);
}

// ---- prep: weights fp32->bf16; bias repacked bf16 [h][nq][g][ti*4+r] * log2(e) ----
__global__ void prep_kernel(const float* __restrict__ qkv_w,
                            const float* __restrict__ proj_w,
                            const float* __restrict__ bias_table,
                            ushort* __restrict__ wq_bf,
                            ushort* __restrict__ wp_bf,
                            ushort* __restrict__ biasb) {
    int i = blockIdx.x * 256 + threadIdx.x;
    if (i < 49152) {
        union { __bf16 b; ushort s; } u; u.b = (__bf16)qkv_w[i];
        wq_bf[i] = u.s;
    }
    if (i < 16384) {
        union { __bf16 b; ushort s; } u; u.b = (__bf16)proj_w[i];
        wp_bf[i] = u.s;
        int h = i >> 12, nq = (i >> 6) & 63, g = (i >> 4) & 3, ti = (i >> 2) & 3, r = i & 3;
        int nk = 16 * ti + 4 * g + r;
        int idx = ((nq >> 3) - (nk >> 3) + 7) * 15 + ((nq & 7) - (nk & 7) + 7);
        union { __bf16 b; ushort s; } ub;
        ub.b = (__bf16)(bias_table[idx * 4 + h] * 1.4426950408889634f);
        biasb[i] = ub.s;
    }
}

__global__ __launch_bounds__(512, 3)
void winattn_mfma(const float* __restrict__ x,
                  const float* __restrict__ qkv_b,
                  const float* __restrict__ proj_b,
                  const ushort* __restrict__ wq_bf,
                  const ushort* __restrict__ wp_bf,
                  const ushort* __restrict__ biasb,
                  float* __restrict__ out) {
    __shared__ ushort S[24576];   // 48KB arena (see header comment)

    const int tid = threadIdx.x;
    const size_t w = blockIdx.x;
    const int h    = __builtin_amdgcn_readfirstlane(tid >> 7);        // 0..3 head
    const int half = __builtin_amdgcn_readfirstlane((tid >> 6) & 1);  // 0..1 wave-in-pair
    const int l  = tid & 63;
    const int g  = (l >> 4) & 3;  // 0..3
    const int cn = l & 15;        // 0..15

    ushort* xs  = S;                       // [64][128] bf16 (phase 1, q-region)
    ushort* qL  = S + 2048 * h;            // [64][32]  (phase 2)
    ushort* kL  = S + 8192 + 2048 * h;     // [64][32]
    ushort* vT  = S + 16384 + 2048 * h;    // [32][64]
    ushort* aoL = S + 16384;               // [64][128] (phase 3, over vT region)

    // ---- stage A: x -> bf16 LDS tile ----
    const float* xg = x + w * 8192;
    #pragma unroll
    for (int it = 0; it < 4; ++it) {
        int f4 = tid + 512 * it;          // 0..2047
        int n = f4 >> 5, c4 = f4 & 31;
        float4 xv = ((const float4*)xg)[f4];
        *(uint2*)&xs[ao_off(n, 4 * c4)] = pack4bf(xv.x, xv.y, xv.z, xv.w);
    }
    __syncthreads();                                   // (1) xs ready

    // ---- stage B: QKV projection MFMAs, d-half = half (acc in regs) ----
    f32x4 aq[4], ak[4], av[4];
    #pragma unroll
    for (int tn = 0; tn < 4; ++tn) {
        aq[tn] = (f32x4){0.f, 0.f, 0.f, 0.f};
        ak[tn] = (f32x4){0.f, 0.f, 0.f, 0.f};
        av[tn] = (f32x4){0.f, 0.f, 0.f, 0.f};
    }
    {
        const int wrow = 32 * h + 16 * half + cn;
        #pragma unroll 2
        for (int kc = 0; kc < 4; ++kc) {
            const bf16x8 wq = *(const bf16x8*)&wq_bf[(size_t)(wrow      ) * 128 + 8 * g + 32 * kc];
            const bf16x8 wk = *(const bf16x8*)&wq_bf[(size_t)(wrow + 128) * 128 + 8 * g + 32 * kc];
            const bf16x8 wv = *(const bf16x8*)&wq_bf[(size_t)(wrow + 256) * 128 + 8 * g + 32 * kc];
            #pragma unroll
            for (int tn = 0; tn < 4; ++tn) {
                const bf16x8 xf = *(const bf16x8*)&xs[ao_off(16 * tn + cn, 8 * g + 32 * kc)];
                aq[tn] = MFMA16(wq, xf, aq[tn]);   // D[d][tok]
                ak[tn] = MFMA16(wk, xf, ak[tn]);   // D[d][tok]
                av[tn] = MFMA16(xf, wv, av[tn]);   // D[tok][d]
            }
        }
    }
    __syncthreads();                                   // (2) xs reads drained

    // ---- write q/k/v (biased) into swizzled tiles ----
    {
        const float4 bq = *(const float4*)&qkv_b[      32 * h + 16 * half + 4 * g];
        const float4 bk = *(const float4*)&qkv_b[128 + 32 * h + 16 * half + 4 * g];
        const float  bv = qkv_b[256 + 32 * h + 16 * half + cn];
        #pragma unroll
        for (int tn = 0; tn < 4; ++tn) {
            f32x4 q4 = aq[tn], k4 = ak[tn], v4 = av[tn];
            *(uint2*)&qL[qk_off(16 * tn + cn, 16 * half + 4 * g)] =
                pack4bf(q4[0] + bq.x, q4[1] + bq.y, q4[2] + bq.z, q4[3] + bq.w);
            *(uint2*)&kL[qk_off(16 * tn + cn, 16 * half + 4 * g)] =
                pack4bf(k4[0] + bk.x, k4[1] + bk.y, k4[2] + bk.z, k4[3] + bk.w);
            *(uint2*)&vT[vt_off(16 * half + cn, 16 * tn + 4 * g)] =
                pack4bf(v4[0] + bv, v4[1] + bv, v4[2] + bv, v4[3] + bv);
        }
    }
    __syncthreads();                                   // (3) q/k/v ready

    // ---- frag loads (must complete before ao overlays vT) ----
    bf16x8 ka[4], qa[2], va[2][2];
    #pragma unroll
    for (int t = 0; t < 4; ++t)
        ka[t] = *(const bf16x8*)&kL[qk_off(16 * t + cn, 8 * g)];
    #pragma unroll
    for (int j2 = 0; j2 < 2; ++j2)
        qa[j2] = *(const bf16x8*)&qL[qk_off(16 * (2 * half + j2) + cn, 8 * g)];
    #pragma unroll
    for (int ta = 0; ta < 2; ++ta)
        #pragma unroll
        for (int kk = 0; kk < 2; ++kk)
            va[ta][kk] = *(const bf16x8*)&vT[vt_off(16 * ta + cn, 8 * g + 32 * kk)];
    __syncthreads();                                   // (4) frag reads drained

    // ---- QK^T (swapped, own tj pair) ----
    f32x4 s[4][2];
    #pragma unroll
    for (int ti = 0; ti < 4; ++ti)
        #pragma unroll
        for (int j2 = 0; j2 < 2; ++j2)
            s[ti][j2] = (f32x4){0.f, 0.f, 0.f, 0.f};
    #pragma unroll
    for (int ti = 0; ti < 4; ++ti)
        #pragma unroll
        for (int j2 = 0; j2 < 2; ++j2)
            s[ti][j2] = MFMA16(ka[ti], qa[j2], s[ti][j2]);   // D[nk][nq]

    // ---- bias load (after QK^T to bound live regs) ----
    uint4 bb[2][2];
    #pragma unroll
    for (int j2 = 0; j2 < 2; ++j2) {
        const int nq = 16 * (2 * half + j2) + cn;
        const ushort* bp = biasb + (((h * 64 + nq) * 4 + g) << 4);
        bb[j2][0] = *(const uint4*)bp;
        bb[j2][1] = *(const uint4*)(bp + 8);
    }

    // ---- softmax (no max-subtract) + in-register P exchange; P UNNORMALIZED ----
    bf16x8 pbf[2][2];
    float rs[2];
    {
        const float SCALE2 = 0.17677669529663687f * 1.4426950408889634f;  // scale*log2(e)
        const int esrc = ((l & 16) << 1) + cn;   // lane 32*(g&1)+cn
        const int osrc = esrc + 16;
        const bool hi = (l & 32) != 0;           // g>=2
        #pragma unroll
        for (int j2 = 0; j2 < 2; ++j2) {
            float sum = 0.f;
            uint2 pk[4];
            #pragma unroll
            for (int ti = 0; ti < 4; ++ti) {
                const uint4 q4 = bb[j2][ti >> 1];
                const unsigned w0 = (ti & 1) ? q4.z : q4.x;
                const unsigned w1 = (ti & 1) ? q4.w : q4.y;
                const float b0 = __uint_as_float(w0 << 16);
                const float b1 = __uint_as_float(w0 & 0xffff0000u);
                const float b2 = __uint_as_float(w1 << 16);
                const float b3 = __uint_as_float(w1 & 0xffff0000u);
                f32x4 sv = s[ti][j2];
                sv[0] = exp2f(fmaf(sv[0], SCALE2, b0));
                sv[1] = exp2f(fmaf(sv[1], SCALE2, b1));
                sv[2] = exp2f(fmaf(sv[2], SCALE2, b2));
                sv[3] = exp2f(fmaf(sv[3], SCALE2, b3));
                pk[ti] = pack4bf(sv[0], sv[1], sv[2], sv[3]);
                sum += (sv[0] + sv[1]) + (sv[2] + sv[3]);
            }
            sum += __shfl_xor(sum, 16, 64);
            sum += __shfl_xor(sum, 32, 64);
            rs[j2] = 1.0f / sum;                 // applied in PV epilogue (lane-local)
            // exchange among 4 lanes {cn+16g}: lane g, slot kk gets
            //   A = pk[(g>>1)+2kk] from lane 32*(g&1)+cn, B = same ti from +16.
            #pragma unroll
            for (int kk = 0; kk < 2; ++kk) {
                uint2 a0 = shfl_u2(pk[2 * kk    ], esrc);
                uint2 a1 = shfl_u2(pk[2 * kk + 1], esrc);
                uint2 b0 = shfl_u2(pk[2 * kk    ], osrc);
                uint2 b1 = shfl_u2(pk[2 * kk + 1], osrc);
                uint2 A; A.x = hi ? a1.x : a0.x; A.y = hi ? a1.y : a0.y;
                uint2 B; B.x = hi ? b1.x : b0.x; B.y = hi ? b1.y : b0.y;
                union { uint4 u; bf16x8 v; } pun;
                pun.u.x = A.x; pun.u.y = A.y; pun.u.z = B.x; pun.u.w = B.y;
                pbf[j2][kk] = pun.v;   // P[nq=16tj+cn][nk = 8g+32kk .. +7], UNNORMALIZED
            }
        }
    }

    // ---- PV (swapped): D[d][nq], both d-halves, own tj pair; scale by rs here ----
    {
        f32x4 o[2][2];
        #pragma unroll
        for (int ta = 0; ta < 2; ++ta)
            #pragma unroll
            for (int j2 = 0; j2 < 2; ++j2)
                o[ta][j2] = (f32x4){0.f, 0.f, 0.f, 0.f};
        #pragma unroll
        for (int kk = 0; kk < 2; ++kk)
            #pragma unroll
            for (int ta = 0; ta < 2; ++ta)
                #pragma unroll
                for (int j2 = 0; j2 < 2; ++j2)
                    o[ta][j2] = MFMA16(va[ta][kk], pbf[j2][kk], o[ta][j2]);
        #pragma unroll
        for (int ta = 0; ta < 2; ++ta)
            #pragma unroll
            for (int j2 = 0; j2 < 2; ++j2) {
                f32x4 ov = o[ta][j2];
                const float r = rs[j2];
                *(uint2*)&aoL[ao_off(16 * (2 * half + j2) + cn, 32 * h + 16 * ta + 4 * g)] =
                    pack4bf(ov[0] * r, ov[1] * r, ov[2] * r, ov[3] * r);
            }
    }
    __syncthreads();                                   // (5) ao ready

    // ---- out projection (swapped), co-block 16*(2h+half) ----
    {
        f32x4 po[4];
        #pragma unroll
        for (int tj = 0; tj < 4; ++tj)
            po[tj] = (f32x4){0.f, 0.f, 0.f, 0.f};
        const int prow = 16 * (2 * h + half) + cn;
        #pragma unroll
        for (int kc = 0; kc < 4; ++kc) {
            const bf16x8 pf = *(const bf16x8*)&wp_bf[(size_t)prow * 128 + 8 * g + 32 * kc];
            #pragma unroll
            for (int tj = 0; tj < 4; ++tj) {
                const bf16x8 aof = *(const bf16x8*)&aoL[ao_off(16 * tj + cn, 8 * g + 32 * kc)];
                po[tj] = MFMA16(pf, aof, po[tj]);
            }
        }
        float* og = out + w * 8192;
        const int co0 = 16 * (2 * h + half) + 4 * g;
        const float4 pb4 = *(const float4*)&proj_b[co0];
        #pragma unroll
        for (int tj = 0; tj < 4; ++tj) {
            f32x4 pv = po[tj];
            float4 ov;
            ov.x = pv[0] + pb4.x; ov.y = pv[1] + pb4.y;
            ov.z = pv[2] + pb4.z; ov.w = pv[3] + pb4.w;
            *(float4*)&og[(16 * tj + cn) * 128 + co0] = ov;
        }
    }
}

extern "C" void kernel_launch(void* const* d_in, const int* in_sizes, int n_in,
                              void* d_out, int out_size, void* d_ws, size_t ws_size,
                              hipStream_t stream) {
    const float* x          = (const float*)d_in[0];
    const float* qkv_w      = (const float*)d_in[1];
    const float* qkv_b      = (const float*)d_in[2];
    const float* proj_w     = (const float*)d_in[3];
    const float* proj_b     = (const float*)d_in[4];
    const float* bias_table = (const float*)d_in[5];
    float* out = (float*)d_out;

    // ws layout: [0,98304) qkv_w bf16 | [98304,131072) proj_w bf16 | [131072,163840) biasb bf16
    ushort* wq_bf = (ushort*)d_ws;
    ushort* wp_bf = (ushort*)((char*)d_ws + 98304);
    ushort* biasb = (ushort*)((char*)d_ws + 131072);

    prep_kernel<<<dim3(192), dim3(256), 0, stream>>>(qkv_w, proj_w, bias_table, wq_bf, wp_bf, biasb);
    winattn_mfma<<<dim3(4096), dim3(512), 0, stream>>>(x, qkv_b, proj_b, wq_bf, wp_bf, biasb, out);
}